// Round 12
// baseline (229.643 us; speedup 1.0000x reference)
//
#include <hip/hip_runtime.h>
#include <stdint.h>
#include <math.h>

using short8 = __attribute__((ext_vector_type(8))) short;
using f32x4  = __attribute__((ext_vector_type(4))) float;

#define DEV __device__ __forceinline__
#define S_VMCNT(n) asm volatile("s_waitcnt vmcnt(" #n ")" ::: "memory")
#define S_LGKM(n)  asm volatile("s_waitcnt lgkmcnt(" #n ")" ::: "memory")
#define S_LGKM0()  asm volatile("s_waitcnt lgkmcnt(0)" ::: "memory")
#define SCHED0()   __builtin_amdgcn_sched_barrier(0)
#define SBAR()     __builtin_amdgcn_s_barrier()

DEV unsigned short f2bf(float f) {
    union { float f; unsigned u; } c; c.f = f;
    unsigned u = c.u;
    unsigned r = (u + 0x7FFFu + ((u >> 16) & 1u)) >> 16;
    return (unsigned short)r;
}

DEV float bf2f(unsigned short h) {
    union { unsigned u; float f; } c; c.u = ((unsigned)h) << 16;
    return c.f;
}

DEV void gld16(const unsigned short* g, unsigned short* l) {
    __builtin_amdgcn_global_load_lds(
        (const __attribute__((address_space(1))) void*)g,
        (__attribute__((address_space(3))) void*)l, 16, 0, 0);
}

DEV unsigned ldsaddr(unsigned short* p) {
    return (unsigned)(uintptr_t)(__attribute__((address_space(3))) unsigned short*)p;
}

DEV unsigned cvtpk(float lo, float hi) {
    unsigned r;
    asm("v_cvt_pk_bf16_f32 %0, %1, %2" : "=v"(r) : "v"(lo), "v"(hi));
    return r;
}

DEV uint2 tr16(unsigned addr) {
    uint2 r;
    asm volatile("ds_read_b64_tr_b16 %0, %1" : "=v"(r) : "v"(addr));
    return r;
}

// ---------------- fused transpose fp32 [768][N] -> bf16 [N][768], 4 weights ----------------
__global__ __launch_bounds__(256) void k_transpose_all(
    const float* __restrict__ w0, const float* __restrict__ w1,
    const float* __restrict__ w2, const float* __restrict__ w3,
    unsigned short* __restrict__ o0, unsigned short* __restrict__ o1,
    unsigned short* __restrict__ o2, unsigned short* __restrict__ o3)
{
    __shared__ float tile[32][33];
    int z = blockIdx.z;
    const float* W = (z == 0) ? w0 : (z == 1) ? w1 : (z == 2) ? w2 : w3;
    unsigned short* Wt = (z == 0) ? o0 : (z == 1) ? o1 : (z == 2) ? o2 : o3;
    int N = (z == 0) ? 2304 : 768;
    int n0 = blockIdx.x * 32, k0 = blockIdx.y * 32;
    if (n0 >= N) return;
    int tx = threadIdx.x, ty = threadIdx.y;
#pragma unroll
    for (int i = 0; i < 4; i++) {
        int k = k0 + ty + i * 8;
        tile[ty + i * 8][tx] = W[(size_t)k * N + n0 + tx];
    }
    __syncthreads();
#pragma unroll
    for (int i = 0; i < 4; i++) {
        int n = n0 + ty + i * 8;
        Wt[(size_t)n * 768 + k0 + tx] = f2bf(tile[tx][ty + i * 8]);
    }
}

// ---------------- layernorm row(768) -> bf16; input f32 (BF=0) or bf16 (BF=1) ----------------
template<int BF>
__global__ __launch_bounds__(256) void k_layernorm(
    const void* __restrict__ xin, const float* __restrict__ g,
    const float* __restrict__ b, unsigned short* __restrict__ out)
{
    int row = blockIdx.x;
    int tid = threadIdx.x;
    float v0, v1, v2;
    if (BF) {
        const unsigned short* xr = (const unsigned short*)xin + (size_t)row * 768;
        v0 = bf2f(xr[tid]); v1 = bf2f(xr[tid + 256]); v2 = bf2f(xr[tid + 512]);
    } else {
        const float* xr = (const float*)xin + (size_t)row * 768;
        v0 = xr[tid]; v1 = xr[tid + 256]; v2 = xr[tid + 512];
    }
    float s1 = v0 + v1 + v2;
    float s2 = v0 * v0 + v1 * v1 + v2 * v2;
#pragma unroll
    for (int off = 32; off >= 1; off >>= 1) {
        s1 += __shfl_down(s1, off);
        s2 += __shfl_down(s2, off);
    }
    __shared__ float red[8];
    int wid = tid >> 6, lane = tid & 63;
    if (lane == 0) { red[wid] = s1; red[4 + wid] = s2; }
    __syncthreads();
    s1 = red[0] + red[1] + red[2] + red[3];
    s2 = red[4] + red[5] + red[6] + red[7];
    float mu = s1 * (1.0f / 768.0f);
    float var = s2 * (1.0f / 768.0f) - mu * mu;
    float rs = rsqrtf(var + 1e-5f);
    unsigned short* orow = out + (size_t)row * 768;
    orow[tid]       = f2bf((v0 - mu) * rs * g[tid]       + b[tid]);
    orow[tid + 256] = f2bf((v1 - mu) * rs * g[tid + 256] + b[tid + 256]);
    orow[tid + 512] = f2bf((v2 - mu) * rs * g[tid + 512] + b[tid + 512]);
}

// ---------------- GEMM: A-in-registers, B-in-LDS ----------------
// A has NO cross-wave reuse (wave owns its 32 rows) -> load A fragments
// straight global->VGPR (per-wave latency, not barrier-coupled). B (weights,
// L2-resident) staged in LDS: 2 buffers, counted vmcnt, 2 barriers/step.
// BN=128: 512 thr (8 waves, wave 32x64).  BN=64: 256 thr (4 waves, wave 32x64).
// EPI 0: qkv scatter  1: proj(+bias+residF -> bf16)  2: fc1(+bias+gelu -> bf16)
// EPI 3: fc2(+bias+residH(bf16) -> f32)
template<int EPI, int BN, int NT>
__global__ __launch_bounds__(NT) void k_gemm(
    const unsigned short* __restrict__ A, const unsigned short* __restrict__ Bt,
    const float* __restrict__ bias,
    const float* __restrict__ residF, const unsigned short* __restrict__ residH,
    float* __restrict__ outF, unsigned short* __restrict__ outH,
    unsigned short* __restrict__ qb, unsigned short* __restrict__ kb,
    unsigned short* __restrict__ vtb)
{
    constexpr int KK = 768, NK = 12;
    constexpr int MI = 2, NJ = 4;
    __shared__ __align__(16) unsigned short Bs[2][BN * 64];   // 16KB or 8KB per buf

    int tid = threadIdx.x;
    int lane = tid & 63, wid = tid >> 6;

    // XCD-aware: each XCD owns a contiguous bx slab, walks by-minor
    int gy = gridDim.y;
    int nwg = 64 * gy;
    int bid = blockIdx.x + blockIdx.y * 64;
    int nid = (bid & 7) * (nwg >> 3) + (bid >> 3);
    int bx = nid / gy;
    int by = nid - bx * gy;
    int m0 = bx * 128, n0 = by * BN;

    int wr = (BN == 128) ? (wid >> 1) * 32 : wid * 32;
    int wc = (BN == 128) ? (wid & 1) * 64 : 0;
    int fr = lane & 15, fg = lane >> 4;
    int fr7 = fr & 7;

    f32x4 zero4 = {0.f, 0.f, 0.f, 0.f};
    f32x4 acc[MI][NJ];
#pragma unroll
    for (int mi = 0; mi < MI; mi++)
#pragma unroll
        for (int nj = 0; nj < NJ; nj++) acc[mi][nj] = zero4;

    // A: direct global->reg fragment loads (lane layout = MFMA A layout)
    const unsigned short* aptr = A + (size_t)(m0 + wr + fr) * KK + fg * 8;

    // B staging: thread t -> row t>>3, LDS chunk t&7 (linear dest);
    // global chunk = (t&7)^(row&7)  [pre-swizzled source, both-sides rule]
    int srow = tid >> 3;
    int schk = (tid & 7) ^ (srow & 7);
    const unsigned short* gb = Bt + (size_t)(n0 + srow) * KK + schk * 8;

    auto stageB = [&](int kt, int s) {
        int ko = kt * 64;
        if constexpr (BN == 128) {   // 512 thr: 2 issues of 64 rows
            gld16(gb + ko, Bs[s] + wid * 512);
            gld16(gb + (size_t)64 * KK + ko, Bs[s] + 4096 + wid * 512);
        } else {                     // 256 thr: 2 issues of 32 rows
            gld16(gb + ko, Bs[s] + wid * 512);
            gld16(gb + (size_t)32 * KK + ko, Bs[s] + 2048 + wid * 512);
        }
    };

    short8 ar[2][MI][2];   // [tile&1][mi][kk], fully static via unroll

    // prologue: B(0) + A(0)
    stageB(0, 0);
    SCHED0();
#pragma unroll
    for (int mi = 0; mi < MI; mi++)
#pragma unroll
        for (int kk = 0; kk < 2; kk++)
            ar[0][mi][kk] = *(const short8*)(aptr + (size_t)mi * 16 * KK + kk * 32);
    SCHED0();

    int boff0 = (wc + fr) * 64;

#pragma unroll
    for (int k = 0; k < NK; ++k) {
        if (k + 1 < NK) {
            stageB(k + 1, (k + 1) & 1);
            SCHED0();
            int ko = (k + 1) * 64;
#pragma unroll
            for (int mi = 0; mi < MI; mi++)
#pragma unroll
                for (int kk = 0; kk < 2; kk++)
                    ar[(k + 1) & 1][mi][kk] =
                        *(const short8*)(aptr + (size_t)mi * 16 * KK + ko + kk * 32);
            SCHED0();
            S_VMCNT(6);   // drain B(k)+A(k) (6 older); B(k+1)+A(k+1) stay in flight
        } else {
            S_VMCNT(0);
        }
        SCHED0(); SBAR(); SCHED0();

        const unsigned short* Bc = Bs[k & 1];
#pragma unroll
        for (int kk = 0; kk < 2; ++kk) {
            int off = (((kk << 2) | fg) ^ fr7) * 8;
            short8 bfv[NJ];
#pragma unroll
            for (int nj = 0; nj < NJ; nj++)
                bfv[nj] = *(const short8*)(Bc + boff0 + nj * 1024 + off);
#pragma unroll
            for (int mi = 0; mi < MI; mi++)
#pragma unroll
                for (int nj = 0; nj < NJ; nj++)
                    acc[mi][nj] = __builtin_amdgcn_mfma_f32_16x16x32_bf16(
                        ar[k & 1][mi][kk], bfv[nj], acc[mi][nj], 0, 0, 0);
        }
        SCHED0(); SBAR(); SCHED0();
    }

#pragma unroll
    for (int mi = 0; mi < MI; mi++) {
#pragma unroll
        for (int nj = 0; nj < NJ; nj++) {
#pragma unroll
            for (int i = 0; i < 4; i++) {
                int grow = m0 + wr + mi * 16 + fg * 4 + i;
                int gcol = n0 + wc + nj * 16 + fr;
                float v = acc[mi][nj][i];
                if (EPI == 0) {
                    int part = gcol / 768;
                    int wi = gcol - part * 768;
                    int head = wi >> 6, d = wi & 63;
                    int bb = grow >> 10, n = grow & 1023;
                    size_t base = ((size_t)(bb * 12 + head)) << 16;
                    unsigned short bv = f2bf(v);
                    if (part == 0)      qb[base + (size_t)n * 64 + d] = bv;
                    else if (part == 1) kb[base + (size_t)n * 64 + d] = bv;
                    else                vtb[base + (size_t)d * 1024 + n] = bv;
                } else if (EPI == 1) {
                    size_t idx = (size_t)grow * 768 + gcol;
                    outH[idx] = f2bf(v + bias[gcol] + residF[idx]);
                } else if (EPI == 2) {
                    float t = v + bias[gcol];
                    outH[(size_t)grow * 768 + gcol] =
                        f2bf(0.5f * t * (1.0f + erff(t * 0.70710678118f)));
                } else {
                    size_t idx = (size_t)grow * 768 + gcol;
                    outF[idx] = v + bias[gcol] + bf2f(residH[idx]);
                }
            }
        }
    }
}

// ---------------- flash attention: 8 waves, 128 q-rows/block, P-pipelined ----------------
// (round-8/9 structure, unchanged)
__global__ __launch_bounds__(512) void k_attn(
    const unsigned short* __restrict__ Q, const unsigned short* __restrict__ Kk,
    const unsigned short* __restrict__ Vt, const int* __restrict__ mask,
    unsigned short* __restrict__ O)
{
    __shared__ __align__(16) unsigned short KsA[3 * 4096];
    __shared__ __align__(16) unsigned short VsA[3 * 4096];
    __shared__ __align__(16) unsigned short PT[8 * 1024];
    __shared__ float mskf[1024];

    int tid = threadIdx.x, lane = tid & 63, wid = tid >> 6;
    int bid = blockIdx.x + blockIdx.y * 8;
    int nid = (bid & 7) * 96 + (bid >> 3);
    int qt = nid & 7;
    int bh = nid >> 3;
    int b = bh / 12;
    int hh = bh - b * 12;
    int fr = lane & 15, fg = lane >> 4;

    const unsigned short* qg = Q  + ((size_t)bh << 16);
    const unsigned short* kg = Kk + ((size_t)bh << 16);
    const unsigned short* vg = Vt + ((size_t)bh << 16);

    for (int i = tid; i < 1024; i += 512)
        mskf[i] = mask[b * 1024 + i] ? 1.f : 0.f;

    short8 qf[2];
    {
        const unsigned short* qp = qg + (size_t)(qt * 128 + wid * 16 + fr) * 64 + fg * 8;
        qf[0] = *(const short8*)(qp);
        qf[1] = *(const short8*)(qp + 32);
    }

    int srow = wid * 8 + (lane >> 3);
    int schk = (lane & 7) ^ ((lane >> 3) & 7);
    const unsigned short* kgp = kg + (size_t)srow * 64 + schk * 8;
    const unsigned short* vgp = vg + (size_t)srow * 1024 + schk * 8;

    auto stage = [&](int kn, int s) {
        gld16(kgp + (size_t)(kn * 64) * 64, &KsA[s * 4096] + wid * 512);
        gld16(vgp + kn * 64, &VsA[s * 4096] + wid * 512);
    };

    stage(0, 0);
    __syncthreads();

    f32x4 zero4 = {0.f, 0.f, 0.f, 0.f};
    f32x4 oacc[4];
    f32x4 lacc = zero4;
#pragma unroll
    for (int df = 0; df < 4; df++) oacc[df] = zero4;

    short8 ones8;
#pragma unroll
    for (int j = 0; j < 8; j++) ones8[j] = (short)0x3F80;

    const float SC = 0.125f * 1.44269504f;

    unsigned short* pw = &PT[wid * 1024];
    unsigned trbase = ldsaddr(pw) + fg * 256 + fr * 2;

    int pos0 = fg ^ (fr & 7);
    int pos1 = (fg + 4) ^ (fr & 7);

#pragma unroll
    for (int kc = 0; kc < 16; ++kc) {
        S_VMCNT(0);
        SCHED0(); SBAR(); SCHED0();
        if (kc < 15) { stage(kc + 1, (kc + 1) % 3); SCHED0(); }

        const unsigned short* Kc = &KsA[(kc % 3) * 4096];
        short8 kb0[4], kb1[4];
#pragma unroll
        for (int nf = 0; nf < 4; ++nf) {
            int row = nf * 16 + fr;
            kb0[nf] = *(const short8*)(Kc + row * 64 + pos0 * 8);
            kb1[nf] = *(const short8*)(Kc + row * 64 + pos1 * 8);
        }
        SCHED0();

        f32x4 s[4];
        if (kc > 0) {
            S_LGKM(8);
            uint2 r00 = tr16(trbase);
            uint2 r01 = tr16(trbase + 128);
            uint2 r10 = tr16(trbase + 1024);
            uint2 r11 = tr16(trbase + 1024 + 128);
            S_LGKM(4);
            SCHED0();
            __builtin_amdgcn_s_setprio(1);
#pragma unroll
            for (int nf = 0; nf < 4; ++nf) {
                f32x4 a = zero4;
                a = __builtin_amdgcn_mfma_f32_16x16x32_bf16(qf[0], kb0[nf], a, 0, 0, 0);
                a = __builtin_amdgcn_mfma_f32_16x16x32_bf16(qf[1], kb1[nf], a, 0, 0, 0);
                s[nf] = a;
            }
            __builtin_amdgcn_s_setprio(0);

            const unsigned short* Vp = &VsA[(((kc - 1) % 3)) * 4096];
            short8 vb0[4], vb1[4];
#pragma unroll
            for (int df = 0; df < 4; ++df) {
                int rv = df * 16 + fr;
                vb0[df] = *(const short8*)(Vp + rv * 64 + pos0 * 8);
                vb1[df] = *(const short8*)(Vp + rv * 64 + pos1 * 8);
            }

            union { unsigned u[4]; short8 s8; } pa0, pa1;
            pa0.u[0] = r00.x; pa0.u[1] = r00.y; pa0.u[2] = r01.x; pa0.u[3] = r01.y;
            pa1.u[0] = r10.x; pa1.u[1] = r10.y; pa1.u[2] = r11.x; pa1.u[3] = r11.y;

            uint2 w[4];
#pragma unroll
            for (int nf = 0; nf < 4; nf++) {
                float mk = mskf[kc * 64 + nf * 16 + fr];
                float p0 = __builtin_amdgcn_exp2f(s[nf][0] * SC) * mk;
                float p1 = __builtin_amdgcn_exp2f(s[nf][1] * SC) * mk;
                float p2 = __builtin_amdgcn_exp2f(s[nf][2] * SC) * mk;
                float p3 = __builtin_amdgcn_exp2f(s[nf][3] * SC) * mk;
                w[nf].x = cvtpk(p0, p1); w[nf].y = cvtpk(p2, p3);
            }

            S_LGKM0();
            SCHED0();
            __builtin_amdgcn_s_setprio(1);
#pragma unroll
            for (int df = 0; df < 4; df++) {
                oacc[df] = __builtin_amdgcn_mfma_f32_16x16x32_bf16(pa0.s8, vb0[df], oacc[df], 0, 0, 0);
                oacc[df] = __builtin_amdgcn_mfma_f32_16x16x32_bf16(pa1.s8, vb1[df], oacc[df], 0, 0, 0);
            }
            lacc = __builtin_amdgcn_mfma_f32_16x16x32_bf16(pa0.s8, ones8, lacc, 0, 0, 0);
            lacc = __builtin_amdgcn_mfma_f32_16x16x32_bf16(pa1.s8, ones8, lacc, 0, 0, 0);
            __builtin_amdgcn_s_setprio(0);

#pragma unroll
            for (int nf = 0; nf < 4; nf++)
                *(uint2*)(pw + (nf * 16 + fr) * 16 + fg * 4) = w[nf];
        } else {
            S_LGKM0();
            SCHED0();
            __builtin_amdgcn_s_setprio(1);
#pragma unroll
            for (int nf = 0; nf < 4; ++nf) {
                f32x4 a = zero4;
                a = __builtin_amdgcn_mfma_f32_16x16x32_bf16(qf[0], kb0[nf], a, 0, 0, 0);
                a = __builtin_amdgcn_mfma_f32_16x16x32_bf16(qf[1], kb1[nf], a, 0, 0, 0);
                s[nf] = a;
            }
            __builtin_amdgcn_s_setprio(0);
#pragma unroll
            for (int nf = 0; nf < 4; nf++) {
                float mk = mskf[nf * 16 + fr];
                float p0 = __builtin_amdgcn_exp2f(s[nf][0] * SC) * mk;
                float p1 = __builtin_amdgcn_exp2f(s[nf][1] * SC) * mk;
                float p2 = __builtin_amdgcn_exp2f(s[nf][2] * SC) * mk;
                float p3 = __builtin_amdgcn_exp2f(s[nf][3] * SC) * mk;
                uint2 w0; w0.x = cvtpk(p0, p1); w0.y = cvtpk(p2, p3);
                *(uint2*)(pw + (nf * 16 + fr) * 16 + fg * 4) = w0;
            }
        }
    }

    {
        uint2 r00 = tr16(trbase);
        uint2 r01 = tr16(trbase + 128);
        uint2 r10 = tr16(trbase + 1024);
        uint2 r11 = tr16(trbase + 1024 + 128);
        const unsigned short* Vp = &VsA[0];
        short8 vb0[4], vb1[4];
#pragma unroll
        for (int df = 0; df < 4; ++df) {
            int rv = df * 16 + fr;
            vb0[df] = *(const short8*)(Vp + rv * 64 + pos0 * 8);
            vb1[df] = *(const short8*)(Vp + rv * 64 + pos1 * 8);
        }
        S_LGKM0(); SCHED0();
        union { unsigned u[4]; short8 s8; } pa0, pa1;
        pa0.u[0] = r00.x; pa0.u[1] = r00.y; pa0.u[2] = r01.x; pa0.u[3] = r01.y;
        pa1.u[0] = r10.x; pa1.u[1] = r10.y; pa1.u[2] = r11.x; pa1.u[3] = r11.y;
#pragma unroll
        for (int df = 0; df < 4; df++) {
            oacc[df] = __builtin_amdgcn_mfma_f32_16x16x32_bf16(pa0.s8, vb0[df], oacc[df], 0, 0, 0);
            oacc[df] = __builtin_amdgcn_mfma_f32_16x16x32_bf16(pa1.s8, vb1[df], oacc[df], 0, 0, 0);
        }
        lacc = __builtin_amdgcn_mfma_f32_16x16x32_bf16(pa0.s8, ones8, lacc, 0, 0, 0);
        lacc = __builtin_amdgcn_mfma_f32_16x16x32_bf16(pa1.s8, ones8, lacc, 0, 0, 0);
    }

#pragma unroll
    for (int i = 0; i < 4; i++) {
        float inv = 1.0f / fmaxf(lacc[i], 1e-30f);
        size_t rowbase = ((size_t)(b * 1024 + qt * 128 + wid * 16 + fg * 4 + i)) * 768
                         + hh * 64 + fr;
#pragma unroll
        for (int df = 0; df < 4; df++)
            O[rowbase + df * 16] = f2bf(oacc[df][i] * inv);
    }
}

// ---------------- launch ----------------
extern "C" void kernel_launch(void* const* d_in, const int* in_sizes, int n_in,
                              void* d_out, int out_size, void* d_ws, size_t ws_size,
                              hipStream_t stream)
{
    const float* x      = (const float*)d_in[0];
    const int*   mask   = (const int*)d_in[1];
    const float* g1     = (const float*)d_in[2];
    const float* b1     = (const float*)d_in[3];
    const float* w_qkv  = (const float*)d_in[4];
    const float* w_proj = (const float*)d_in[5];
    const float* b_proj = (const float*)d_in[6];
    const float* g2     = (const float*)d_in[7];
    const float* b2     = (const float*)d_in[8];
    const float* w_fc1  = (const float*)d_in[9];
    const float* b_fc1  = (const float*)d_in[10];
    const float* w_fc2  = (const float*)d_in[11];
    const float* b_fc2  = (const float*)d_in[12];
    float* out = (float*)d_out;

    char* ws = (char*)d_ws;
    unsigned short* wqkv_t  = (unsigned short*)(ws + 0);
    unsigned short* wproj_t = (unsigned short*)(ws + 3538944);
    unsigned short* wfc1_t  = (unsigned short*)(ws + 4718592);
    unsigned short* wfc2_t  = (unsigned short*)(ws + 5898240);
    unsigned short* bufA    = (unsigned short*)(ws + 7077888);   // h / h2
    unsigned short* bufB    = (unsigned short*)(ws + 19660800);  // o / gelu-out
    unsigned short* qb      = (unsigned short*)(ws + 32243712);
    unsigned short* kb      = (unsigned short*)(ws + 44826624);
    unsigned short* vtb     = (unsigned short*)(ws + 57409536);
    unsigned short* x1b     = (unsigned short*)(ws + 69992448);  // bf16 residual trunk
    // total < 95,158,272 bytes

    k_transpose_all<<<dim3(72, 24, 4), dim3(32, 8), 0, stream>>>(
        w_qkv, w_proj, w_fc1, w_fc2, wqkv_t, wproj_t, wfc1_t, wfc2_t);

    k_layernorm<0><<<8192, 256, 0, stream>>>(x, g1, b1, bufA);

    k_gemm<0, 128, 512><<<dim3(64, 18), 512, 0, stream>>>(bufA, wqkv_t,
        nullptr, nullptr, nullptr, nullptr, nullptr, qb, kb, vtb);

    k_attn<<<dim3(8, 96), 512, 0, stream>>>(qb, kb, vtb, mask, bufB);

    k_gemm<1, 64, 256><<<dim3(64, 12), 256, 0, stream>>>(bufB, wproj_t,
        b_proj, x, nullptr, nullptr, x1b, nullptr, nullptr, nullptr);

    k_layernorm<1><<<8192, 256, 0, stream>>>(x1b, g2, b2, bufA);

    k_gemm<2, 64, 256><<<dim3(64, 12), 256, 0, stream>>>(bufA, wfc1_t,
        b_fc1, nullptr, nullptr, nullptr, bufB, nullptr, nullptr, nullptr);

    k_gemm<3, 64, 256><<<dim3(64, 12), 256, 0, stream>>>(bufB, wfc2_t,
        b_fc2, nullptr, x1b, out, nullptr, nullptr, nullptr, nullptr);
}

// Round 13
// 158.950 us; speedup vs baseline: 1.4448x; 1.4448x over previous
//
#include <hip/hip_runtime.h>
#include <stdint.h>
#include <math.h>

using short8 = __attribute__((ext_vector_type(8))) short;
using f32x4  = __attribute__((ext_vector_type(4))) float;

#define DEV __device__ __forceinline__
#define S_VMCNT(n) asm volatile("s_waitcnt vmcnt(" #n ")" ::: "memory")
#define S_LGKM(n)  asm volatile("s_waitcnt lgkmcnt(" #n ")" ::: "memory")
#define S_LGKM0()  asm volatile("s_waitcnt lgkmcnt(0)" ::: "memory")
#define SCHED0()   __builtin_amdgcn_sched_barrier(0)
#define SBAR()     __builtin_amdgcn_s_barrier()

DEV unsigned short f2bf(float f) {
    union { float f; unsigned u; } c; c.f = f;
    unsigned u = c.u;
    unsigned r = (u + 0x7FFFu + ((u >> 16) & 1u)) >> 16;
    return (unsigned short)r;
}

DEV float bf2f(unsigned short h) {
    union { unsigned u; float f; } c; c.u = ((unsigned)h) << 16;
    return c.f;
}

DEV void gld16(const unsigned short* g, unsigned short* l) {
    __builtin_amdgcn_global_load_lds(
        (const __attribute__((address_space(1))) void*)g,
        (__attribute__((address_space(3))) void*)l, 16, 0, 0);
}

DEV unsigned ldsaddr(unsigned short* p) {
    return (unsigned)(uintptr_t)(__attribute__((address_space(3))) unsigned short*)p;
}

DEV unsigned cvtpk(float lo, float hi) {
    unsigned r;
    asm("v_cvt_pk_bf16_f32 %0, %1, %2" : "=v"(r) : "v"(lo), "v"(hi));
    return r;
}

DEV uint2 tr16(unsigned addr) {
    uint2 r;
    asm volatile("ds_read_b64_tr_b16 %0, %1" : "=v"(r) : "v"(addr));
    return r;
}

// ---------------- prep: LN1 (+bf16 copy of x) fused with 4 weight transposes ----------------
// blocks 0..8191: layernorm rows (also emit xb = bf16(x));
// blocks 8192.. : fp32 [768][N] -> bf16 [N][768] transpose tiles.
__global__ __launch_bounds__(256) void k_prep(
    const float* __restrict__ x, const float* __restrict__ g,
    const float* __restrict__ b, unsigned short* __restrict__ h_out,
    unsigned short* __restrict__ xb,
    const float* __restrict__ w0, const float* __restrict__ w1,
    const float* __restrict__ w2, const float* __restrict__ w3,
    unsigned short* __restrict__ o0, unsigned short* __restrict__ o1,
    unsigned short* __restrict__ o2, unsigned short* __restrict__ o3)
{
    __shared__ float tile[32][33];
    __shared__ float red[8];
    int bid = blockIdx.x;
    int tid = threadIdx.x;

    if (bid < 8192) {
        int row = bid;
        const float* xr = x + (size_t)row * 768;
        float v0 = xr[tid], v1 = xr[tid + 256], v2 = xr[tid + 512];
        float s1 = v0 + v1 + v2;
        float s2 = v0 * v0 + v1 * v1 + v2 * v2;
#pragma unroll
        for (int off = 32; off >= 1; off >>= 1) {
            s1 += __shfl_down(s1, off);
            s2 += __shfl_down(s2, off);
        }
        int wid = tid >> 6, lane = tid & 63;
        if (lane == 0) { red[wid] = s1; red[4 + wid] = s2; }
        __syncthreads();
        s1 = red[0] + red[1] + red[2] + red[3];
        s2 = red[4] + red[5] + red[6] + red[7];
        float mu = s1 * (1.0f / 768.0f);
        float var = s2 * (1.0f / 768.0f) - mu * mu;
        float rs = rsqrtf(var + 1e-5f);
        unsigned short* orow = h_out + (size_t)row * 768;
        unsigned short* xrow = xb + (size_t)row * 768;
        orow[tid]       = f2bf((v0 - mu) * rs * g[tid]       + b[tid]);
        orow[tid + 256] = f2bf((v1 - mu) * rs * g[tid + 256] + b[tid + 256]);
        orow[tid + 512] = f2bf((v2 - mu) * rs * g[tid + 512] + b[tid + 512]);
        xrow[tid]       = f2bf(v0);
        xrow[tid + 256] = f2bf(v1);
        xrow[tid + 512] = f2bf(v2);
    } else {
        int idx = bid - 8192;
        const float* W; unsigned short* Wt; int N, n0, k0;
        if (idx < 1728) {
            W = w0; Wt = o0; N = 2304;
            n0 = (idx % 72) * 32; k0 = (idx / 72) * 32;
        } else {
            idx -= 1728;
            int z = idx / 576, r = idx % 576;
            W = (z == 0) ? w1 : (z == 1) ? w2 : w3;
            Wt = (z == 0) ? o1 : (z == 1) ? o2 : o3;
            N = 768;
            n0 = (r % 24) * 32; k0 = (r / 24) * 32;
        }
        int tx = tid & 31, ty = tid >> 5;
#pragma unroll
        for (int i = 0; i < 4; i++) {
            int k = k0 + ty + i * 8;
            tile[ty + i * 8][tx] = W[(size_t)k * N + n0 + tx];
        }
        __syncthreads();
#pragma unroll
        for (int i = 0; i < 4; i++) {
            int n = n0 + ty + i * 8;
            Wt[(size_t)n * 768 + k0 + tx] = f2bf(tile[tx][ty + i * 8]);
        }
    }
}

// ---------------- layernorm row(768) -> bf16; input bf16 ----------------
__global__ __launch_bounds__(256) void k_layernorm_bf(
    const unsigned short* __restrict__ xin, const float* __restrict__ g,
    const float* __restrict__ b, unsigned short* __restrict__ out)
{
    int row = blockIdx.x;
    int tid = threadIdx.x;
    const unsigned short* xr = xin + (size_t)row * 768;
    float v0 = bf2f(xr[tid]), v1 = bf2f(xr[tid + 256]), v2 = bf2f(xr[tid + 512]);
    float s1 = v0 + v1 + v2;
    float s2 = v0 * v0 + v1 * v1 + v2 * v2;
#pragma unroll
    for (int off = 32; off >= 1; off >>= 1) {
        s1 += __shfl_down(s1, off);
        s2 += __shfl_down(s2, off);
    }
    __shared__ float red[8];
    int wid = tid >> 6, lane = tid & 63;
    if (lane == 0) { red[wid] = s1; red[4 + wid] = s2; }
    __syncthreads();
    s1 = red[0] + red[1] + red[2] + red[3];
    s2 = red[4] + red[5] + red[6] + red[7];
    float mu = s1 * (1.0f / 768.0f);
    float var = s2 * (1.0f / 768.0f) - mu * mu;
    float rs = rsqrtf(var + 1e-5f);
    unsigned short* orow = out + (size_t)row * 768;
    orow[tid]       = f2bf((v0 - mu) * rs * g[tid]       + b[tid]);
    orow[tid + 256] = f2bf((v1 - mu) * rs * g[tid + 256] + b[tid + 256]);
    orow[tid + 512] = f2bf((v2 - mu) * rs * g[tid + 512] + b[tid + 512]);
}

// ---------------- GEMM (round-9 proven schedule): BK=64, 2 LDS bufs, counted vmcnt ----
// BN=128: 8 waves (512 thr), wave 32x64. BN=64: 4 waves (256 thr), wave 32x64.
// EPI 0: qkv scatter (v-part via LDS transpose -> coalesced vtb stores)
// EPI 1: proj(+bias+residH(bf16 x) -> bf16)  2: fc1(+bias+gelu -> bf16)
// EPI 3: fc2(+bias+residH(bf16) -> f32)
template<int EPI, int BN>
__global__ __launch_bounds__(BN == 128 ? 512 : 256) void k_gemm(
    const unsigned short* __restrict__ A, const unsigned short* __restrict__ Bt,
    const float* __restrict__ bias, const unsigned short* __restrict__ residH,
    float* __restrict__ outF, unsigned short* __restrict__ outH,
    unsigned short* __restrict__ qb, unsigned short* __restrict__ kb,
    unsigned short* __restrict__ vtb)
{
    constexpr int KK = 768, NK = 12;
    constexpr int MI = 2;
    constexpr int NJ = 4;
    __shared__ __align__(16) unsigned short As[2][128 * 64];
    __shared__ __align__(16) unsigned short Bs[2][BN * 64];

    int tid = threadIdx.x;
    int lane = tid & 63, wid = tid >> 6;

    // XCD-aware: each XCD owns a contiguous bx slab, walks by-minor
    int gy = gridDim.y;
    int nwg = 64 * gy;
    int bid = blockIdx.x + blockIdx.y * 64;
    int nid = (bid & 7) * (nwg >> 3) + (bid >> 3);
    int bx = nid / gy;
    int by = nid - bx * gy;
    int m0 = bx * 128, n0 = by * BN;

    int wr = (BN == 128) ? (wid >> 1) * 32 : wid * 32;
    int wc = (BN == 128) ? (wid & 1) * 64 : 0;
    int fr = lane & 15, fg = lane >> 4;
    int fr7 = fr & 7;

    f32x4 zero4 = {0.f, 0.f, 0.f, 0.f};
    f32x4 acc[MI][NJ];
#pragma unroll
    for (int mi = 0; mi < MI; mi++)
#pragma unroll
        for (int nj = 0; nj < NJ; nj++) acc[mi][nj] = zero4;

    // staging: thread t -> row t>>3, LDS chunk t&7 (linear); global chunk
    // (t&7)^(row&7) [pre-swizzled source, both-sides rule]
    int srow = tid >> 3;
    int schk = (tid & 7) ^ ((tid >> 3) & 7);
    const unsigned short* ga = A  + (size_t)(m0 + srow) * KK + schk * 8;
    const unsigned short* gb = Bt + (size_t)(n0 + srow) * KK + schk * 8;

    auto stage = [&](int kt, int s) {
        int ko = kt * 64;
        if constexpr (BN == 128) {
            gld16(ga + ko, As[s] + wid * 512);
            gld16(ga + (size_t)64 * KK + ko, As[s] + 4096 + wid * 512);
            gld16(gb + ko, Bs[s] + wid * 512);
            gld16(gb + (size_t)64 * KK + ko, Bs[s] + 4096 + wid * 512);
        } else {
#pragma unroll
            for (int i = 0; i < 4; i++)
                gld16(ga + (size_t)i * 32 * KK + ko, As[s] + i * 2048 + wid * 512);
#pragma unroll
            for (int i = 0; i < 2; i++)
                gld16(gb + (size_t)i * 32 * KK + ko, Bs[s] + i * 2048 + wid * 512);
        }
    };

    int aoff0 = (wr + fr) * 64;
    int boff0 = (wc + fr) * 64;

    stage(0, 0);

    for (int k = 0; k < NK; ++k) {
        if (k + 1 < NK) {
            stage(k + 1, (k + 1) & 1);
            if constexpr (BN == 128) { S_VMCNT(4); } else { S_VMCNT(6); }
        } else {
            S_VMCNT(0);
        }
        SCHED0(); SBAR(); SCHED0();

        const unsigned short* Ac = As[k & 1];
        const unsigned short* Bc = Bs[k & 1];
#pragma unroll
        for (int kk = 0; kk < 2; ++kk) {
            int off = (((kk << 2) | fg) ^ fr7) * 8;
            short8 af[MI], bfv[NJ];
#pragma unroll
            for (int mi = 0; mi < MI; mi++)
                af[mi] = *(const short8*)(Ac + aoff0 + mi * 1024 + off);
#pragma unroll
            for (int nj = 0; nj < NJ; nj++)
                bfv[nj] = *(const short8*)(Bc + boff0 + nj * 1024 + off);
#pragma unroll
            for (int mi = 0; mi < MI; mi++)
#pragma unroll
                for (int nj = 0; nj < NJ; nj++)
                    acc[mi][nj] = __builtin_amdgcn_mfma_f32_16x16x32_bf16(
                        af[mi], bfv[nj], acc[mi][nj], 0, 0, 0);
        }
        SCHED0(); SBAR(); SCHED0();
    }

    if (EPI == 0 && n0 >= 1536) {
        // v-part block: transpose C through LDS, then coalesced vtb stores.
        // Safe to reuse As: all waves passed the trailing SBAR => all LDS reads done.
        unsigned short* Ct = &As[0][0];   // 128x128 bf16 = 32 KB
#pragma unroll
        for (int mi = 0; mi < MI; mi++) {
#pragma unroll
            for (int nj = 0; nj < NJ; nj++) {
                int row = wc + nj * 16 + fr;            // = gcol - n0
                int colb = wr + mi * 16 + fg * 4;       // = grow - m0 (base of 4)
                int ch = (colb >> 3) ^ (row & 15);
                uint2 w;
                w.x = cvtpk(acc[mi][nj][0], acc[mi][nj][1]);
                w.y = cvtpk(acc[mi][nj][2], acc[mi][nj][3]);
                *(uint2*)(Ct + row * 128 + ch * 8 + (colb & 7)) = w;
            }
        }
        __syncthreads();
        int r = tid >> 2;                                // 0..127 (d-row)
        int h0 = (n0 - 1536) >> 6;
        int bb = m0 >> 10;
        int nbase = m0 & 1023;
        size_t vbase = ((size_t)(bb * 12 + h0 + (r >> 6)) << 16)
                     + (size_t)(r & 63) * 1024 + nbase;
#pragma unroll
        for (int j = 0; j < 4; j++) {
            int c = (tid & 3) * 4 + j;
            int ch = c ^ (r & 15);
            uint4 v4 = *(const uint4*)(Ct + r * 128 + ch * 8);
            *(uint4*)(vtb + vbase + c * 8) = v4;
        }
        return;
    }

#pragma unroll
    for (int mi = 0; mi < MI; mi++) {
#pragma unroll
        for (int nj = 0; nj < NJ; nj++) {
#pragma unroll
            for (int i = 0; i < 4; i++) {
                int grow = m0 + wr + mi * 16 + fg * 4 + i;
                int gcol = n0 + wc + nj * 16 + fr;
                float v = acc[mi][nj][i];
                if (EPI == 0) {
                    // q/k blocks only (v handled above)
                    int part = gcol / 768;
                    int wi = gcol - part * 768;
                    int head = wi >> 6, d = wi & 63;
                    int bb = grow >> 10, n = grow & 1023;
                    size_t base = ((size_t)(bb * 12 + head)) << 16;
                    unsigned short bv = f2bf(v);
                    if (part == 0) qb[base + (size_t)n * 64 + d] = bv;
                    else           kb[base + (size_t)n * 64 + d] = bv;
                } else if (EPI == 1) {
                    size_t idx = (size_t)grow * 768 + gcol;
                    outH[idx] = f2bf(v + bias[gcol] + bf2f(residH[idx]));
                } else if (EPI == 2) {
                    float t = v + bias[gcol];
                    outH[(size_t)grow * 768 + gcol] =
                        f2bf(0.5f * t * (1.0f + erff(t * 0.70710678118f)));
                } else {
                    size_t idx = (size_t)grow * 768 + gcol;
                    outF[idx] = v + bias[gcol] + bf2f(residH[idx]);
                }
            }
        }
    }
}

// ---------------- flash attention: 8 waves, 128 q-rows/block, P-pipelined ----------------
// (round-8/9 structure, unchanged)
__global__ __launch_bounds__(512) void k_attn(
    const unsigned short* __restrict__ Q, const unsigned short* __restrict__ Kk,
    const unsigned short* __restrict__ Vt, const int* __restrict__ mask,
    unsigned short* __restrict__ O)
{
    __shared__ __align__(16) unsigned short KsA[3 * 4096];
    __shared__ __align__(16) unsigned short VsA[3 * 4096];
    __shared__ __align__(16) unsigned short PT[8 * 1024];
    __shared__ float mskf[1024];

    int tid = threadIdx.x, lane = tid & 63, wid = tid >> 6;
    int bid = blockIdx.x + blockIdx.y * 8;
    int nid = (bid & 7) * 96 + (bid >> 3);
    int qt = nid & 7;
    int bh = nid >> 3;
    int b = bh / 12;
    int hh = bh - b * 12;
    int fr = lane & 15, fg = lane >> 4;

    const unsigned short* qg = Q  + ((size_t)bh << 16);
    const unsigned short* kg = Kk + ((size_t)bh << 16);
    const unsigned short* vg = Vt + ((size_t)bh << 16);

    for (int i = tid; i < 1024; i += 512)
        mskf[i] = mask[b * 1024 + i] ? 1.f : 0.f;

    short8 qf[2];
    {
        const unsigned short* qp = qg + (size_t)(qt * 128 + wid * 16 + fr) * 64 + fg * 8;
        qf[0] = *(const short8*)(qp);
        qf[1] = *(const short8*)(qp + 32);
    }

    int srow = wid * 8 + (lane >> 3);
    int schk = (lane & 7) ^ ((lane >> 3) & 7);
    const unsigned short* kgp = kg + (size_t)srow * 64 + schk * 8;
    const unsigned short* vgp = vg + (size_t)srow * 1024 + schk * 8;

    auto stage = [&](int kn, int s) {
        gld16(kgp + (size_t)(kn * 64) * 64, &KsA[s * 4096] + wid * 512);
        gld16(vgp + kn * 64, &VsA[s * 4096] + wid * 512);
    };

    stage(0, 0);
    __syncthreads();

    f32x4 zero4 = {0.f, 0.f, 0.f, 0.f};
    f32x4 oacc[4];
    f32x4 lacc = zero4;
#pragma unroll
    for (int df = 0; df < 4; df++) oacc[df] = zero4;

    short8 ones8;
#pragma unroll
    for (int j = 0; j < 8; j++) ones8[j] = (short)0x3F80;

    const float SC = 0.125f * 1.44269504f;

    unsigned short* pw = &PT[wid * 1024];
    unsigned trbase = ldsaddr(pw) + fg * 256 + fr * 2;

    int pos0 = fg ^ (fr & 7);
    int pos1 = (fg + 4) ^ (fr & 7);

#pragma unroll
    for (int kc = 0; kc < 16; ++kc) {
        S_VMCNT(0);
        SCHED0(); SBAR(); SCHED0();
        if (kc < 15) { stage(kc + 1, (kc + 1) % 3); SCHED0(); }

        const unsigned short* Kc = &KsA[(kc % 3) * 4096];
        short8 kb0[4], kb1[4];
#pragma unroll
        for (int nf = 0; nf < 4; ++nf) {
            int row = nf * 16 + fr;
            kb0[nf] = *(const short8*)(Kc + row * 64 + pos0 * 8);
            kb1[nf] = *(const short8*)(Kc + row * 64 + pos1 * 8);
        }
        SCHED0();

        f32x4 s[4];
        if (kc > 0) {
            S_LGKM(8);
            uint2 r00 = tr16(trbase);
            uint2 r01 = tr16(trbase + 128);
            uint2 r10 = tr16(trbase + 1024);
            uint2 r11 = tr16(trbase + 1024 + 128);
            S_LGKM(4);
            SCHED0();
            __builtin_amdgcn_s_setprio(1);
#pragma unroll
            for (int nf = 0; nf < 4; ++nf) {
                f32x4 a = zero4;
                a = __builtin_amdgcn_mfma_f32_16x16x32_bf16(qf[0], kb0[nf], a, 0, 0, 0);
                a = __builtin_amdgcn_mfma_f32_16x16x32_bf16(qf[1], kb1[nf], a, 0, 0, 0);
                s[nf] = a;
            }
            __builtin_amdgcn_s_setprio(0);

            const unsigned short* Vp = &VsA[(((kc - 1) % 3)) * 4096];
            short8 vb0[4], vb1[4];
#pragma unroll
            for (int df = 0; df < 4; ++df) {
                int rv = df * 16 + fr;
                vb0[df] = *(const short8*)(Vp + rv * 64 + pos0 * 8);
                vb1[df] = *(const short8*)(Vp + rv * 64 + pos1 * 8);
            }

            union { unsigned u[4]; short8 s8; } pa0, pa1;
            pa0.u[0] = r00.x; pa0.u[1] = r00.y; pa0.u[2] = r01.x; pa0.u[3] = r01.y;
            pa1.u[0] = r10.x; pa1.u[1] = r10.y; pa1.u[2] = r11.x; pa1.u[3] = r11.y;

            uint2 w[4];
#pragma unroll
            for (int nf = 0; nf < 4; nf++) {
                float mk = mskf[kc * 64 + nf * 16 + fr];
                float p0 = __builtin_amdgcn_exp2f(s[nf][0] * SC) * mk;
                float p1 = __builtin_amdgcn_exp2f(s[nf][1] * SC) * mk;
                float p2 = __builtin_amdgcn_exp2f(s[nf][2] * SC) * mk;
                float p3 = __builtin_amdgcn_exp2f(s[nf][3] * SC) * mk;
                w[nf].x = cvtpk(p0, p1); w[nf].y = cvtpk(p2, p3);
            }

            S_LGKM0();
            SCHED0();
            __builtin_amdgcn_s_setprio(1);
#pragma unroll
            for (int df = 0; df < 4; df++) {
                oacc[df] = __builtin_amdgcn_mfma_f32_16x16x32_bf16(pa0.s8, vb0[df], oacc[df], 0, 0, 0);
                oacc[df] = __builtin_amdgcn_mfma_f32_16x16x32_bf16(pa1.s8, vb1[df], oacc[df], 0, 0, 0);
            }
            lacc = __builtin_amdgcn_mfma_f32_16x16x32_bf16(pa0.s8, ones8, lacc, 0, 0, 0);
            lacc = __builtin_amdgcn_mfma_f32_16x16x32_bf16(pa1.s8, ones8, lacc, 0, 0, 0);
            __builtin_amdgcn_s_setprio(0);

#pragma unroll
            for (int nf = 0; nf < 4; nf++)
                *(uint2*)(pw + (nf * 16 + fr) * 16 + fg * 4) = w[nf];
        } else {
            S_LGKM0();
            SCHED0();
            __builtin_amdgcn_s_setprio(1);
#pragma unroll
            for (int nf = 0; nf < 4; ++nf) {
                f32x4 a = zero4;
                a = __builtin_amdgcn_mfma_f32_16x16x32_bf16(qf[0], kb0[nf], a, 0, 0, 0);
                a = __builtin_amdgcn_mfma_f32_16x16x32_bf16(qf[1], kb1[nf], a, 0, 0, 0);
                s[nf] = a;
            }
            __builtin_amdgcn_s_setprio(0);
#pragma unroll
            for (int nf = 0; nf < 4; nf++) {
                float mk = mskf[nf * 16 + fr];
                float p0 = __builtin_amdgcn_exp2f(s[nf][0] * SC) * mk;
                float p1 = __builtin_amdgcn_exp2f(s[nf][1] * SC) * mk;
                float p2 = __builtin_amdgcn_exp2f(s[nf][2] * SC) * mk;
                float p3 = __builtin_amdgcn_exp2f(s[nf][3] * SC) * mk;
                uint2 w0; w0.x = cvtpk(p0, p1); w0.y = cvtpk(p2, p3);
                *(uint2*)(pw + (nf * 16 + fr) * 16 + fg * 4) = w0;
            }
        }
    }

    {
        uint2 r00 = tr16(trbase);
        uint2 r01 = tr16(trbase + 128);
        uint2 r10 = tr16(trbase + 1024);
        uint2 r11 = tr16(trbase + 1024 + 128);
        const unsigned short* Vp = &VsA[0];
        short8 vb0[4], vb1[4];
#pragma unroll
        for (int df = 0; df < 4; ++df) {
            int rv = df * 16 + fr;
            vb0[df] = *(const short8*)(Vp + rv * 64 + pos0 * 8);
            vb1[df] = *(const short8*)(Vp + rv * 64 + pos1 * 8);
        }
        S_LGKM0(); SCHED0();
        union { unsigned u[4]; short8 s8; } pa0, pa1;
        pa0.u[0] = r00.x; pa0.u[1] = r00.y; pa0.u[2] = r01.x; pa0.u[3] = r01.y;
        pa1.u[0] = r10.x; pa1.u[1] = r10.y; pa1.u[2] = r11.x; pa1.u[3] = r11.y;
#pragma unroll
        for (int df = 0; df < 4; df++) {
            oacc[df] = __builtin_amdgcn_mfma_f32_16x16x32_bf16(pa0.s8, vb0[df], oacc[df], 0, 0, 0);
            oacc[df] = __builtin_amdgcn_mfma_f32_16x16x32_bf16(pa1.s8, vb1[df], oacc[df], 0, 0, 0);
        }
        lacc = __builtin_amdgcn_mfma_f32_16x16x32_bf16(pa0.s8, ones8, lacc, 0, 0, 0);
        lacc = __builtin_amdgcn_mfma_f32_16x16x32_bf16(pa1.s8, ones8, lacc, 0, 0, 0);
    }

#pragma unroll
    for (int i = 0; i < 4; i++) {
        float inv = 1.0f / fmaxf(lacc[i], 1e-30f);
        size_t rowbase = ((size_t)(b * 1024 + qt * 128 + wid * 16 + fg * 4 + i)) * 768
                         + hh * 64 + fr;
#pragma unroll
        for (int df = 0; df < 4; df++)
            O[rowbase + df * 16] = f2bf(oacc[df][i] * inv);
    }
}

// ---------------- launch ----------------
extern "C" void kernel_launch(void* const* d_in, const int* in_sizes, int n_in,
                              void* d_out, int out_size, void* d_ws, size_t ws_size,
                              hipStream_t stream)
{
    const float* x      = (const float*)d_in[0];
    const int*   mask   = (const int*)d_in[1];
    const float* g1     = (const float*)d_in[2];
    const float* b1     = (const float*)d_in[3];
    const float* w_qkv  = (const float*)d_in[4];
    const float* w_proj = (const float*)d_in[5];
    const float* b_proj = (const float*)d_in[6];
    const float* g2     = (const float*)d_in[7];
    const float* b2     = (const float*)d_in[8];
    const float* w_fc1  = (const float*)d_in[9];
    const float* b_fc1  = (const float*)d_in[10];
    const float* w_fc2  = (const float*)d_in[11];
    const float* b_fc2  = (const float*)d_in[12];
    float* out = (float*)d_out;

    char* ws = (char*)d_ws;
    unsigned short* wqkv_t  = (unsigned short*)(ws + 0);
    unsigned short* wproj_t = (unsigned short*)(ws + 3538944);
    unsigned short* wfc1_t  = (unsigned short*)(ws + 4718592);
    unsigned short* wfc2_t  = (unsigned short*)(ws + 5898240);
    unsigned short* bufA    = (unsigned short*)(ws + 7077888);   // h / h2
    unsigned short* bufB    = (unsigned short*)(ws + 19660800);  // o / gelu-out
    unsigned short* qb      = (unsigned short*)(ws + 32243712);
    unsigned short* kb      = (unsigned short*)(ws + 44826624);
    unsigned short* vtb     = (unsigned short*)(ws + 57409536);
    unsigned short* x1b     = (unsigned short*)(ws + 69992448);  // bf16 residual trunk
    unsigned short* xb      = (unsigned short*)(ws + 82575360);  // bf16 copy of x
    // total = 95,158,272 bytes

    k_prep<<<8192 + 3456, 256, 0, stream>>>(x, g1, b1, bufA, xb,
        w_qkv, w_proj, w_fc1, w_fc2, wqkv_t, wproj_t, wfc1_t, wfc2_t);

    k_gemm<0, 128><<<dim3(64, 18), 512, 0, stream>>>(bufA, wqkv_t,
        nullptr, nullptr, nullptr, nullptr, qb, kb, vtb);

    k_attn<<<dim3(8, 96), 512, 0, stream>>>(qb, kb, vtb, mask, bufB);

    k_gemm<1, 64><<<dim3(64, 12), 256, 0, stream>>>(bufB, wproj_t,
        b_proj, xb, nullptr, x1b, nullptr, nullptr, nullptr);

    k_layernorm_bf<<<8192, 256, 0, stream>>>(x1b, g2, b2, bufA);

    k_gemm<2, 64><<<dim3(64, 12), 256, 0, stream>>>(bufA, wfc1_t,
        b_fc1, nullptr, nullptr, bufB, nullptr, nullptr, nullptr);

    k_gemm<3, 64><<<dim3(64, 12), 256, 0, stream>>>(bufB, wfc2_t,
        b_fc2, x1b, out, nullptr, nullptr, nullptr, nullptr);
}